// Round 1
// baseline (373.758 us; speedup 1.0000x reference)
//
#include <hip/hip_runtime.h>
#include <math.h>

// ---- constants ----
#define SLf   0.22360679774997896f   // sqrt(L), L = 0.05
#define CSPH  0.8862269254527580f    // sqrt(pi)/2

// ---- quadrature tables (filled by init_tables on every launch; deterministic) ----
__device__ float d_A48[48], d_W48[48];     // 48-pt GL on [0,1]
__device__ float d_A32[32], d_W32[32];     // 32-pt GL on [0,1]
__device__ float d_R32[32], d_WQE32[32];   // r = -log1p(-a32), w/(1-a32)
__device__ float d_C0;

// ================= init: Gauss-Legendre nodes via Newton (f64) =================
__device__ void gl_node(int n, int i, double* x01, double* w01) {
    double z = cos(3.14159265358979323846 * ((double)i + 0.75) / ((double)n + 0.5));
    for (int it = 0; it < 8; ++it) {
        double pm = 1.0, pl = z;
        for (int k = 2; k <= n; ++k) {
            double pk = ((2.0 * k - 1.0) * z * pl - (k - 1.0) * pm) / (double)k;
            pm = pl; pl = pk;
        }
        double pp = (double)n * (z * pl - pm) / (z * z - 1.0);
        z -= pl / pp;
    }
    double pm = 1.0, pl = z;
    for (int k = 2; k <= n; ++k) {
        double pk = ((2.0 * k - 1.0) * z * pl - (k - 1.0) * pm) / (double)k;
        pm = pl; pl = pk;
    }
    double pp = (double)n * (z * pl - pm) / (z * z - 1.0);
    *x01 = 0.5 * (z + 1.0);
    *w01 = 1.0 / ((1.0 - z * z) * pp * pp);   // (2/((1-z^2)pp^2)) / 2  (map to [0,1])
}

__device__ double g_dbl(double x) {
    if (x >= -3.0) return 0.8862269254527580 * exp(x * x) * (1.0 + erf(x));
    double z = -x, iz2 = 1.0 / (z * z);
    return (0.5 / z) * (1.0 + iz2 * (-0.5 + iz2 * (0.75 - 1.875 * iz2)));
}

__global__ void init_tables() {
    int i = threadIdx.x;   // 64 threads = 1 wave
    if (i < 48) {
        double x, w; gl_node(48, i, &x, &w);
        d_A48[i] = (float)x; d_W48[i] = (float)w;
    }
    if (i < 32) {
        double x, w; gl_node(32, i, &x, &w);
        d_A32[i] = (float)x; d_W32[i] = (float)w;
        d_R32[i] = (float)(-log1p(-x));
        d_WQE32[i] = (float)(w / (1.0 - x));
    }
    // C0 = int_{-inf}^0 exp(-s^2) g(s)^2 ds  via 64-pt rule, r = -log1p(-q)
    double x, w; gl_node(64, i, &x, &w);
    double r = -log1p(-x);
    double gv = g_dbl(-r);
    double term = w * exp(-r * r) * gv * gv / (1.0 - x);
    for (int off = 32; off > 0; off >>= 1)
        term += __shfl_down(term, off);
    if (i == 0) d_C0 = (float)term;
}

// ================= fast f32 math =================
__device__ __forceinline__ float frcp(float x) { return __builtin_amdgcn_rcpf(x); }

// A&S 7.1.26: for z >= 0, erfcx(z) = erfc(z)*exp(z^2) ~= P(t), t = 1/(1+0.3275911 z)
__device__ __forceinline__ float erfcx_poly(float z) {
    float t = frcp(fmaf(0.3275911f, z, 1.0f));
    return t * (0.254829592f + t * (-0.284496736f + t * (1.421413741f +
           t * (-1.453152027f + t * 1.061405429f))));
}

// g(y) for y <= 0 (matches reference branch at -3: direct vs asymptotic)
__device__ __forceinline__ float g_negarg(float y) {
    float z = -y;                          // >= 0
    float direct = CSPH * erfcx_poly(z);   // C * exp(y^2)(1+erf(y)) = C*erfcx(-y), no exp needed
    float iz = frcp(z);
    float iz2 = iz * iz;
    float asym = 0.5f * iz * (1.0f + iz2 * (-0.5f + iz2 * (0.75f - 1.875f * iz2)));
    return (y >= -3.0f) ? direct : asym;
}

// g(x), any sign
__device__ __forceinline__ float g_any(float x) {
    if (x >= 0.0f) {
        float E = __expf(x * x);
        return CSPH * (2.0f * E - erfcx_poly(x));   // C*e^{x^2}(1+erf x) = C(2e^{x^2} - erfcx(x))
    }
    return g_negarg(x);
}

// H_neg(x) for x <= 0:  x * sum_i W_i * h(x*a_i),
// h(t) = sum_j [W_j/(1-q_j)] * exp((2t-r_j)*r_j) * g(t-r_j)^2
__device__ float H_neg_f(float x) {
    float acc = 0.0f;
    for (int i = 0; i < 32; ++i) {
        float t = x * d_A32[i];
        float h = 0.0f;
        for (int j = 0; j < 32; ++j) {
            float r = d_R32[j];
            float gg = g_negarg(t - r);          // arg always <= 0
            float e = __expf((2.0f * t - r) * r);
            h = fmaf(d_WQE32[j], e * gg * gg, h);
        }
        acc = fmaf(d_W32[i], h, acc);
    }
    return x * acc;
}

// H_pos(x) for x >= 0: C0*E(x) + x^2 * sum_i W_i a_i e^{t^2} * inner(t),  t = x a_i
// inner(t) = sum_j W_j exp(-s^2) g(s)^2,  s = t b_j  (b == a, 32-pt)
__device__ float H_pos_f(float x) {
    float E = 0.0f;
    for (int k = 0; k < 48; ++k) {
        float t = x * d_A48[k];
        E = fmaf(d_W48[k], __expf(t * t), E);
    }
    E *= x;
    float acc = 0.0f;
    for (int i = 0; i < 32; ++i) {
        float t = x * d_A32[i];
        float inner = 0.0f;
        for (int j = 0; j < 32; ++j) {
            float sj = t * d_A32[j];
            float Es = __expf(sj * sj);
            float gs = CSPH * (2.0f * Es - erfcx_poly(sj));   // g(sj), sj >= 0
            inner = fmaf(d_W32[j], gs * gs * frcp(Es), inner); // * exp(-sj^2)
        }
        acc = fmaf(d_W32[i] * d_A32[i], __expf(t * t) * inner, acc);
    }
    return d_C0 * E + x * x * acc;
}

// ================= main kernel =================
__global__ __launch_bounds__(256) void mnn_main(const float* __restrict__ U,
        const float* __restrict__ S, float* __restrict__ out, int n) {
    int idx = blockIdx.x * blockDim.x + threadIdx.x;
    if (idx >= n) return;
    float u = U[idx], s = S[idx];
    float ua = 0.0f, sa = 0.0f, chi = 0.0f;

    bool sgt0 = (s > 0.0f);
    bool reg1 = sgt0 && ((1.0f - u) < 10.0f * SLf * s);   // VT*L = 1, CUT*SL*s

    if (reg1) {
        float inv = 1.0f / (SLf * s);
        float ub = (1.0f - u) * inv;
        float lb = -u * inv;                    // always <= 0

        // dG = G(ub) - G(lb), merged 48-pt loops
        float sGub = 0.0f, sGlb = 0.0f;
        for (int k = 0; k < 48; ++k) {
            float a = d_A48[k], w = d_W48[k];
            sGub = fmaf(w, g_any(ub * a), sGub);
            sGlb = fmaf(w, g_negarg(lb * a), sGlb);
        }
        float dG = ub * sGub - lb * sGlb;
        float ua1 = 1.0f / (40.0f * dG + 5.0f); // (2/L)*dG + TREF

        // dH = H(ub) - H_neg(lb)
        float Hub = (ub >= 0.0f) ? H_pos_f(ub) : H_neg_f(ub);
        float Hlb = H_neg_f(lb);
        float dH = Hub - Hlb;

        float fano = 3200.0f * dH * ua1 * ua1;  // 8/L^2 = 3200
        float val = fano * ua1;
        float s_a = (val > 0.0f) ? sqrtf(val) : 0.0f;

        float dg = g_any(ub) - g_negarg(lb);
        float sa_safe = (s_a > 0.0f) ? s_a : 1.0f;
        chi = ua1 * ua1 * dg * 178.88543819998318f / sa_safe;  // 2/L^1.5
        ua = ua1; sa = s_a;
    } else if (!sgt0 && u > 1.0f) {            // region 2
        float logt = 5.0f - 20.0f * logf(1.0f - 1.0f / u);
        ua = 1.0f / logt;
        chi = 6.324555320336759f / (sqrtf(logt) * sqrtf(2.0f * u - 1.0f)); // sqrt(2/L)=sqrt(40)
    }
    // region 0 (& !reg2): all zeros (fano=1 but val=fano*0=0 -> s_a=0)

    out[idx] = ua;
    out[n + idx] = sa;
    out[2 * n + idx] = chi;
}

// ================= launch =================
extern "C" void kernel_launch(void* const* d_in, const int* in_sizes, int n_in,
                              void* d_out, int out_size, void* d_ws, size_t ws_size,
                              hipStream_t stream) {
    const float* u = (const float*)d_in[0];
    const float* s = (const float*)d_in[1];
    float* out = (float*)d_out;
    int n = in_sizes[0];

    init_tables<<<dim3(1), dim3(64), 0, stream>>>();
    mnn_main<<<dim3((n + 255) / 256), dim3(256), 0, stream>>>(u, s, out, n);
}

// Round 2
// 137.718 us; speedup vs baseline: 2.7139x; 2.7139x over previous
//
#include <hip/hip_runtime.h>
#include <math.h>

// ---- constants ----
#define SLf   0.22360679774997896f   // sqrt(L), L = 0.05

// ---- table geometry ----
#define NTAB  8192
#define XMIN  -17.0
#define XMAX  6.0
// dx = (XMAX-XMIN)/(NTAB-1)

__device__ double dd_A48[48], dd_W48[48];
__device__ double dd_A32[32], dd_W32[32];
__device__ double dd_R32[32], dd_WQE32[32];
__device__ double dd_C0;

__device__ float gtab[NTAB];   // g(x)
__device__ float Gtab[NTAB];   // G(x) = int_0^x g
__device__ float Htab[NTAB];   // H(x)  (H_pos for x>=0, H_neg for x<0)

// ================= init 0: Gauss-Legendre nodes via Newton (f64) =================
__device__ void gl_node(int n, int i, double* x01, double* w01) {
    double z = cos(3.14159265358979323846 * ((double)i + 0.75) / ((double)n + 0.5));
    for (int it = 0; it < 8; ++it) {
        double pm = 1.0, pl = z;
        for (int k = 2; k <= n; ++k) {
            double pk = ((2.0 * k - 1.0) * z * pl - (k - 1.0) * pm) / (double)k;
            pm = pl; pl = pk;
        }
        double pp = (double)n * (z * pl - pm) / (z * z - 1.0);
        z -= pl / pp;
    }
    double pm = 1.0, pl = z;
    for (int k = 2; k <= n; ++k) {
        double pk = ((2.0 * k - 1.0) * z * pl - (k - 1.0) * pm) / (double)k;
        pm = pl; pl = pk;
    }
    double pp = (double)n * (z * pl - pm) / (z * z - 1.0);
    *x01 = 0.5 * (z + 1.0);
    *w01 = 1.0 / ((1.0 - z * z) * pp * pp);   // weight mapped to [0,1]
}

// g(x) in f64 with exact erf (matches reference branch structure at -3)
__device__ double g_dbl(double x) {
    if (x >= -3.0) return 0.8862269254527580 * exp(x * x) * (1.0 + erf(x));
    double z = -x, iz2 = 1.0 / (z * z);
    return (0.5 / z) * (1.0 + iz2 * (-0.5 + iz2 * (0.75 - 1.875 * iz2)));
}

__global__ void init_nodes() {
    int i = threadIdx.x;   // 64 threads = 1 wave
    if (i < 48) {
        double x, w; gl_node(48, i, &x, &w);
        dd_A48[i] = x; dd_W48[i] = w;
    }
    if (i < 32) {
        double x, w; gl_node(32, i, &x, &w);
        dd_A32[i] = x; dd_W32[i] = w;
        dd_R32[i] = -log1p(-x);
        dd_WQE32[i] = w / (1.0 - x);
    }
    // C0 = int_{-inf}^0 exp(-s^2) g(s)^2 ds, 64-pt, r = -log1p(-q)
    double x, w; gl_node(64, i, &x, &w);
    double r = -log1p(-x);
    double gv = g_dbl(-r);
    double term = w * exp(-r * r) * gv * gv / (1.0 - x);
    for (int off = 32; off > 0; off >>= 1)
        term += __shfl_down(term, off);
    if (i == 0) dd_C0 = term;
}

// ================= init 1: g and G tables (one thread per entry) =================
__global__ __launch_bounds__(256) void init_gG() {
    int k = blockIdx.x * blockDim.x + threadIdx.x;
    if (k >= NTAB) return;
    const double dx = (XMAX - XMIN) / (double)(NTAB - 1);
    double x = XMIN + dx * (double)k;
    gtab[k] = (float)g_dbl(x);
    double acc = 0.0;
    for (int i = 0; i < 48; ++i)
        acc += dd_W48[i] * g_dbl(x * dd_A48[i]);
    Gtab[k] = (float)(x * acc);
}

// ================= init 2: H table (32 threads per entry, one per outer node) ===
__global__ __launch_bounds__(256) void init_H() {
    int gid = blockIdx.x * blockDim.x + threadIdx.x;
    int k = gid >> 5;          // table entry
    int i = gid & 31;          // outer quadrature node
    if (k >= NTAB) return;
    const double dx = (XMAX - XMIN) / (double)(NTAB - 1);
    double x = XMIN + dx * (double)k;

    double partial;
    if (x < 0.0) {
        // H_neg: partial_i = W_i * h(x*a_i); h(t) = sum_j WQE_j exp((2t-r)r) g(t-r)^2
        double t = x * dd_A32[i];
        double h = 0.0;
        for (int j = 0; j < 32; ++j) {
            double r = dd_R32[j];
            double gg = g_dbl(t - r);
            h += dd_WQE32[j] * exp((2.0 * t - r) * r) * gg * gg;
        }
        partial = dd_W32[i] * h;
    } else {
        // H_pos tail: partial_i = W_i * a_i * e^{t^2} * sum_j W_j e^{-s^2} g(s)^2
        double t = x * dd_A32[i];
        double inner = 0.0;
        for (int j = 0; j < 32; ++j) {
            double s = t * dd_A32[j];
            double gs = g_dbl(s);
            inner += dd_W32[j] * exp(-s * s) * gs * gs;
        }
        partial = dd_W32[i] * dd_A32[i] * exp(t * t) * inner;
    }
    // reduce across the 32 lanes of this entry
    for (int off = 16; off > 0; off >>= 1)
        partial += __shfl_down(partial, off, 32);

    if (i == 0) {
        double H;
        if (x < 0.0) {
            H = x * partial;
        } else {
            double E = 0.0;
            for (int q = 0; q < 48; ++q) {
                double t = x * dd_A48[q];
                E += dd_W48[q] * exp(t * t);
            }
            E *= x;
            H = dd_C0 * E + x * x * partial;
        }
        Htab[k] = (float)H;
    }
}

// ================= main kernel: table lookups =================
__device__ __forceinline__ float interp(const float* __restrict__ tab, float x) {
    const float INV_DX = (float)((NTAB - 1) / (XMAX - XMIN));
    float t = (x - (float)XMIN) * INV_DX;
    t = fminf(fmaxf(t, 1.0f), (float)(NTAB - 3));
    int k = (int)t;
    if (k > NTAB - 3) k = NTAB - 3;
    float f = t - (float)k;
    float p0 = tab[k - 1], p1 = tab[k], p2 = tab[k + 1], p3 = tab[k + 2];
    // Catmull-Rom cubic
    return p1 + 0.5f * f * (p2 - p0 + f * (2.0f * p0 - 5.0f * p1 + 4.0f * p2 - p3
                 + f * (3.0f * (p1 - p2) + p3 - p0)));
}

__global__ __launch_bounds__(256) void mnn_main(const float* __restrict__ U,
        const float* __restrict__ S, float* __restrict__ out, int n) {
    int idx = blockIdx.x * blockDim.x + threadIdx.x;
    if (idx >= n) return;
    float u = U[idx], s = S[idx];
    float ua = 0.0f, sa = 0.0f, chi = 0.0f;

    bool sgt0 = (s > 0.0f);
    bool reg1 = sgt0 && ((1.0f - u) < 10.0f * SLf * s);   // VT*L = 1

    if (reg1) {
        float inv = 1.0f / (SLf * s);
        float ub = (1.0f - u) * inv;
        float lb = -u * inv;                    // always <= 0

        float dG = interp(Gtab, ub) - interp(Gtab, lb);
        float ua1 = 1.0f / (40.0f * dG + 5.0f); // (2/L)*dG + TREF

        float dH = interp(Htab, ub) - interp(Htab, lb);

        float fano = 3200.0f * dH * ua1 * ua1;  // 8/L^2
        float val = fano * ua1;
        float s_a = (val > 0.0f) ? sqrtf(val) : 0.0f;

        float dg = interp(gtab, ub) - interp(gtab, lb);
        float sa_safe = (s_a > 0.0f) ? s_a : 1.0f;
        chi = ua1 * ua1 * dg * 178.88543819998318f / sa_safe;  // 2/L^1.5
        ua = ua1; sa = s_a;
    } else if (!sgt0 && u > 1.0f) {            // region 2
        float logt = 5.0f - 20.0f * logf(1.0f - 1.0f / u);
        ua = 1.0f / logt;
        chi = 6.324555320336759f / (sqrtf(logt) * sqrtf(2.0f * u - 1.0f)); // sqrt(40)
    }

    out[idx] = ua;
    out[n + idx] = sa;
    out[2 * n + idx] = chi;
}

// ================= launch =================
extern "C" void kernel_launch(void* const* d_in, const int* in_sizes, int n_in,
                              void* d_out, int out_size, void* d_ws, size_t ws_size,
                              hipStream_t stream) {
    const float* u = (const float*)d_in[0];
    const float* s = (const float*)d_in[1];
    float* out = (float*)d_out;
    int n = in_sizes[0];

    init_nodes<<<dim3(1), dim3(64), 0, stream>>>();
    init_gG<<<dim3((NTAB + 255) / 256), dim3(256), 0, stream>>>();
    init_H<<<dim3((NTAB * 32 + 255) / 256), dim3(256), 0, stream>>>();
    mnn_main<<<dim3((n + 255) / 256), dim3(256), 0, stream>>>(u, s, out, n);
}

// Round 3
// 44.596 us; speedup vs baseline: 8.3809x; 3.0881x over previous
//
#include <hip/hip_runtime.h>
#include <math.h>

// ---- constants ----
#define SLf   0.22360679774997896f   // sqrt(L), L = 0.05

// ---- table geometry ----
#define NTAB  8192
#define XMIN  -17.0
#define XMAX  6.0

__device__ double dd_A48[48], dd_W48[48];
__device__ double dd_A32[32], dd_W32[32];
__device__ double dd_R32[32], dd_WQE32[32];
__device__ double dd_C0;

__device__ double htab[NTAB];      // h(x) = exp(x^2) * int_{-inf}^x e^{-s^2} g^2  (ref 32-pt r-rule)
__device__ double innertab[NTAB];  // inner(t) = sum_j W32_j e^{-s^2} g(s)^2, s = t*b_j
__device__ float  gtab[NTAB];      // g(x)
__device__ float  Gtab[NTAB];      // G(x)
__device__ float  Htab[NTAB];      // H(x)

// ================= f64 special functions =================
__device__ double g_dbl(double x) {
    if (x >= -3.0) return 0.8862269254527580 * exp(x * x) * (1.0 + erf(x));
    double z = -x, iz2 = 1.0 / (z * z);
    return (0.5 / z) * (1.0 + iz2 * (-0.5 + iz2 * (0.75 - 1.875 * iz2)));
}

// ================= init 0: GL nodes, one Newton solve per thread =================
template <int N>
__device__ void gl_node_t(int i, const double* __restrict__ inv, double* x01, double* w01) {
    double z = cos(3.14159265358979323846 * ((double)i + 0.75) / ((double)N + 0.5));
    double pl = z, pm = 1.0, pp = 1.0;
    for (int it = 0; it < 6; ++it) {
        pm = 1.0; pl = z;
        #pragma unroll
        for (int k = 2; k <= N; ++k) {
            double pk = ((2.0 * k - 1.0) * z * pl - (k - 1.0) * pm) * inv[k];
            pm = pl; pl = pk;
        }
        pp = (double)N * (z * pl - pm) / (z * z - 1.0);
        z -= pl / pp;
    }
    pm = 1.0; pl = z;
    #pragma unroll
    for (int k = 2; k <= N; ++k) {
        double pk = ((2.0 * k - 1.0) * z * pl - (k - 1.0) * pm) * inv[k];
        pm = pl; pl = pk;
    }
    pp = (double)N * (z * pl - pm) / (z * z - 1.0);
    *x01 = 0.5 * (z + 1.0);
    *w01 = 1.0 / ((1.0 - z * z) * pp * pp);   // weight mapped to [0,1]
}

__global__ void init_nodes() {
    __shared__ double s_inv[65];
    int i = threadIdx.x;                       // 256 threads
    if (i >= 2 && i <= 64) s_inv[i] = 1.0 / (double)i;
    __syncthreads();

    if (i < 48) {                              // wave 0: GL-48
        double x, w; gl_node_t<48>(i, s_inv, &x, &w);
        dd_A48[i] = x; dd_W48[i] = w;
    } else if (i >= 64 && i < 96) {            // wave 1: GL-32 (+derived)
        int j = i - 64;
        double x, w; gl_node_t<32>(j, s_inv, &x, &w);
        dd_A32[j] = x; dd_W32[j] = w;
        dd_R32[j] = -log1p(-x);
        dd_WQE32[j] = w / (1.0 - x);
    } else if (i >= 128 && i < 192) {          // wave 2: GL-64 -> C0
        int j = i - 128;
        double x, w; gl_node_t<64>(j, s_inv, &x, &w);
        double r = -log1p(-x);
        double gv = g_dbl(-r);
        double term = w * exp(-r * r) * gv * gv / (1.0 - x);
        for (int off = 32; off > 0; off >>= 1)
            term += __shfl_down(term, off);
        if (j == 0) dd_C0 = term;
    }
}

// ================= init 1: g, G, h, inner tables (4 threads per entry) ===========
__global__ __launch_bounds__(256) void init_tabs() {
    int gid = blockIdx.x * blockDim.x + threadIdx.x;
    int k = gid >> 2, p = gid & 3;
    if (k >= NTAB) return;
    const double dx = (XMAX - XMIN) / (double)(NTAB - 1);
    double x = XMIN + dx * (double)k;

    // G chunk: 12 of 48 nodes
    double aG = 0.0;
    for (int q = 12 * p; q < 12 * p + 12; ++q)
        aG += dd_W48[q] * g_dbl(x * dd_A48[q]);

    // h chunk: 8 of 32 nodes (reference _h_neg integrand; valid for any x)
    double ah = 0.0;
    for (int j = 8 * p; j < 8 * p + 8; ++j) {
        double r = dd_R32[j];
        double gg = g_dbl(x - r);
        ah += dd_WQE32[j] * exp((2.0 * x - r) * r) * gg * gg;
    }

    // inner chunk: 8 of 32 nodes (reference H_pos inner integrand)
    double ai = 0.0;
    for (int j = 8 * p; j < 8 * p + 8; ++j) {
        double s = x * dd_A32[j];
        double gs = g_dbl(s);
        ai += dd_W32[j] * exp(-s * s) * gs * gs;
    }

    // reduce over the 4 lanes of this entry
    aG += __shfl_xor(aG, 1, 4); aG += __shfl_xor(aG, 2, 4);
    ah += __shfl_xor(ah, 1, 4); ah += __shfl_xor(ah, 2, 4);
    ai += __shfl_xor(ai, 1, 4); ai += __shfl_xor(ai, 2, 4);

    if (p == 0) {
        Gtab[k] = (float)(x * aG);
        htab[k] = ah;
        innertab[k] = ai;
        gtab[k] = (float)g_dbl(x);
    }
}

// f64 Catmull-Rom interp over a uniform table
__device__ __forceinline__ double interpd(const double* __restrict__ tab, double x) {
    const double INV_DX = (double)(NTAB - 1) / (XMAX - XMIN);
    double t = (x - XMIN) * INV_DX;
    t = fmin(fmax(t, 1.0), (double)(NTAB - 3));
    int k = (int)t;
    if (k > NTAB - 3) k = NTAB - 3;
    double f = t - (double)k;
    double p0 = tab[k - 1], p1 = tab[k], p2 = tab[k + 1], p3 = tab[k + 2];
    return p1 + 0.5 * f * (p2 - p0 + f * (2.0 * p0 - 5.0 * p1 + 4.0 * p2 - p3
               + f * (3.0 * (p1 - p2) + p3 - p0)));
}

// ================= init 2: H table via outer rules over interpolated h/inner =====
__global__ __launch_bounds__(256) void init_H() {
    int k = blockIdx.x * blockDim.x + threadIdx.x;
    if (k >= NTAB) return;
    const double dx = (XMAX - XMIN) / (double)(NTAB - 1);
    double x = XMIN + dx * (double)k;

    double H;
    if (x < 0.0) {
        // H_neg(x) = x * sum_i W_i h(x*a_i)
        double acc = 0.0;
        for (int i = 0; i < 32; ++i)
            acc += dd_W32[i] * interpd(htab, x * dd_A32[i]);
        H = x * acc;
    } else {
        // H_pos(x) = C0*E(x) + x^2 sum_i W_i a_i e^{t^2} inner(t), t = x*a_i
        double E = 0.0;
        for (int q = 0; q < 48; ++q) {
            double t = x * dd_A48[q];
            E += dd_W48[q] * exp(t * t);
        }
        E *= x;
        double S = 0.0;
        for (int i = 0; i < 32; ++i) {
            double t = x * dd_A32[i];
            S += dd_W32[i] * dd_A32[i] * exp(t * t) * interpd(innertab, t);
        }
        H = dd_C0 * E + x * x * S;
    }
    Htab[k] = (float)H;
}

// ================= main kernel: table lookups =================
__device__ __forceinline__ float interpf(const float* __restrict__ tab, float x) {
    const float INV_DX = (float)((NTAB - 1) / (XMAX - XMIN));
    float t = (x - (float)XMIN) * INV_DX;
    t = fminf(fmaxf(t, 1.0f), (float)(NTAB - 3));
    int k = (int)t;
    if (k > NTAB - 3) k = NTAB - 3;
    float f = t - (float)k;
    float p0 = tab[k - 1], p1 = tab[k], p2 = tab[k + 1], p3 = tab[k + 2];
    return p1 + 0.5f * f * (p2 - p0 + f * (2.0f * p0 - 5.0f * p1 + 4.0f * p2 - p3
                 + f * (3.0f * (p1 - p2) + p3 - p0)));
}

__global__ __launch_bounds__(256) void mnn_main(const float* __restrict__ U,
        const float* __restrict__ S, float* __restrict__ out, int n) {
    int idx = blockIdx.x * blockDim.x + threadIdx.x;
    if (idx >= n) return;
    float u = U[idx], s = S[idx];
    float ua = 0.0f, sa = 0.0f, chi = 0.0f;

    bool sgt0 = (s > 0.0f);
    bool reg1 = sgt0 && ((1.0f - u) < 10.0f * SLf * s);   // VT*L = 1

    if (reg1) {
        float inv = 1.0f / (SLf * s);
        float ub = (1.0f - u) * inv;
        float lb = -u * inv;                    // always <= 0

        float dG = interpf(Gtab, ub) - interpf(Gtab, lb);
        float ua1 = 1.0f / (40.0f * dG + 5.0f); // (2/L)*dG + TREF

        float dH = interpf(Htab, ub) - interpf(Htab, lb);

        float fano = 3200.0f * dH * ua1 * ua1;  // 8/L^2
        float val = fano * ua1;
        float s_a = (val > 0.0f) ? sqrtf(val) : 0.0f;

        float dg = interpf(gtab, ub) - interpf(gtab, lb);
        float sa_safe = (s_a > 0.0f) ? s_a : 1.0f;
        chi = ua1 * ua1 * dg * 178.88543819998318f / sa_safe;  // 2/L^1.5
        ua = ua1; sa = s_a;
    } else if (!sgt0 && u > 1.0f) {            // region 2
        float logt = 5.0f - 20.0f * logf(1.0f - 1.0f / u);
        ua = 1.0f / logt;
        chi = 6.324555320336759f / (sqrtf(logt) * sqrtf(2.0f * u - 1.0f)); // sqrt(40)
    }

    out[idx] = ua;
    out[n + idx] = sa;
    out[2 * n + idx] = chi;
}

// ================= launch =================
extern "C" void kernel_launch(void* const* d_in, const int* in_sizes, int n_in,
                              void* d_out, int out_size, void* d_ws, size_t ws_size,
                              hipStream_t stream) {
    const float* u = (const float*)d_in[0];
    const float* s = (const float*)d_in[1];
    float* out = (float*)d_out;
    int n = in_sizes[0];

    init_nodes<<<dim3(1), dim3(256), 0, stream>>>();
    init_tabs<<<dim3((NTAB * 4 + 255) / 256), dim3(256), 0, stream>>>();
    init_H<<<dim3((NTAB + 255) / 256), dim3(256), 0, stream>>>();
    mnn_main<<<dim3((n + 255) / 256), dim3(256), 0, stream>>>(u, s, out, n);
}

// Round 4
// 30.514 us; speedup vs baseline: 12.2488x; 1.4615x over previous
//
#include <hip/hip_runtime.h>
#include <math.h>

// ---- constants ----
#define SLf   0.22360679774997896f   // sqrt(L), L = 0.05

// ---- table geometry ----
#define NTAB   2048
#define XMIN   -17.0
#define XMAX   6.0
#define XMINf  -17.0f
#define DXf    (23.0f / 2047.0f)
#define INVDXf (2047.0f / 23.0f)

__device__ double dd_A48[48], dd_W48[48];
__device__ double dd_A32[32], dd_W32[32];
__device__ double dd_R32[32], dd_WQE32[32];
// f32 copies for the table builders
__device__ float f_A48[48], f_W48[48];
__device__ float f_A32[32], f_W32[32];
__device__ float f_R32[32], f_WQE32[32];
__device__ float f_C0;

__device__ float  htabf[NTAB];     // h(x): ref 32-pt r-rule integrand sum
__device__ float  innertabf[NTAB]; // inner(t) = sum_j W32_j e^{-s^2} g(s)^2
__device__ float4 tab4[NTAB];      // .x = g, .y = G, .z = H

// ================= f64 g (only for C0) =================
__device__ double g_dbl(double x) {
    if (x >= -3.0) return 0.8862269254527580 * exp(x * x) * (1.0 + erf(x));
    double z = -x, iz2 = 1.0 / (z * z);
    return (0.5 / z) * (1.0 + iz2 * (-0.5 + iz2 * (0.75 - 1.875 * iz2)));
}

// ================= f32 g: erfc-based, cancellation-free =================
__device__ __forceinline__ float g_f32(float x) {
    if (x >= -3.0f) {
        // sqrt(pi)/2 * e^{x^2} * (1+erf(x)) = C * e^{x^2} * erfc(-x)
        return 0.88622692545275801f * __expf(x * x) * erfcf(-x);
    }
    float z = -x, iz = 1.0f / z, iz2 = iz * iz;
    return 0.5f * iz * (1.0f + iz2 * (-0.5f + iz2 * (0.75f - 1.875f * iz2)));
}

// ================= init 0: GL nodes, one Newton solve per thread =================
template <int N>
__device__ void gl_node_t(int i, const double* __restrict__ inv, double* x01, double* w01) {
    double z = cos(3.14159265358979323846 * ((double)i + 0.75) / ((double)N + 0.5));
    double pl = z, pm = 1.0, pp = 1.0;
    for (int it = 0; it < 6; ++it) {
        pm = 1.0; pl = z;
        #pragma unroll
        for (int k = 2; k <= N; ++k) {
            double pk = ((2.0 * k - 1.0) * z * pl - (k - 1.0) * pm) * inv[k];
            pm = pl; pl = pk;
        }
        pp = (double)N * (z * pl - pm) / (z * z - 1.0);
        z -= pl / pp;
    }
    pm = 1.0; pl = z;
    #pragma unroll
    for (int k = 2; k <= N; ++k) {
        double pk = ((2.0 * k - 1.0) * z * pl - (k - 1.0) * pm) * inv[k];
        pm = pl; pl = pk;
    }
    pp = (double)N * (z * pl - pm) / (z * z - 1.0);
    *x01 = 0.5 * (z + 1.0);
    *w01 = 1.0 / ((1.0 - z * z) * pp * pp);   // weight mapped to [0,1]
}

__global__ void init_nodes() {
    __shared__ double s_inv[65];
    int i = threadIdx.x;                       // 256 threads
    if (i >= 2 && i <= 64) s_inv[i] = 1.0 / (double)i;
    __syncthreads();

    if (i < 48) {                              // wave 0: GL-48
        double x, w; gl_node_t<48>(i, s_inv, &x, &w);
        dd_A48[i] = x; dd_W48[i] = w;
        f_A48[i] = (float)x; f_W48[i] = (float)w;
    } else if (i >= 64 && i < 96) {            // wave 1: GL-32 (+derived)
        int j = i - 64;
        double x, w; gl_node_t<32>(j, s_inv, &x, &w);
        dd_A32[j] = x; dd_W32[j] = w;
        f_A32[j] = (float)x; f_W32[j] = (float)w;
        f_R32[j] = (float)(-log1p(-x));
        f_WQE32[j] = (float)(w / (1.0 - x));
    } else if (i >= 128 && i < 192) {          // wave 2: GL-64 -> C0
        int j = i - 128;
        double x, w; gl_node_t<64>(j, s_inv, &x, &w);
        double r = -log1p(-x);
        double gv = g_dbl(-r);
        double term = w * exp(-r * r) * gv * gv / (1.0 - x);
        for (int off = 32; off > 0; off >>= 1)
            term += __shfl_down(term, off);
        if (j == 0) f_C0 = (float)term;
    }
}

// ================= init 1: g, G, h, inner tables (4 lanes per entry, f32) =======
__global__ __launch_bounds__(256) void init_tabs() {
    int gid = blockIdx.x * blockDim.x + threadIdx.x;
    int k = gid >> 2, p = gid & 3;
    if (k >= NTAB) return;
    float x = XMINf + DXf * (float)k;

    // G chunk: 12 of 48 nodes
    float aG = 0.0f;
    for (int q = 12 * p; q < 12 * p + 12; ++q)
        aG = fmaf(f_W48[q], g_f32(x * f_A48[q]), aG);

    // h chunk: 8 of 32 nodes (reference _h_neg integrand)
    float ah = 0.0f;
    for (int j = 8 * p; j < 8 * p + 8; ++j) {
        float r = f_R32[j];
        float gg = g_f32(x - r);
        ah = fmaf(f_WQE32[j], __expf((2.0f * x - r) * r) * gg * gg, ah);
    }

    // inner chunk: 8 of 32 nodes (reference H_pos inner integrand)
    float ai = 0.0f;
    for (int j = 8 * p; j < 8 * p + 8; ++j) {
        float s = x * f_A32[j];
        float gs = g_f32(s);
        ai = fmaf(f_W32[j], __expf(-s * s) * gs * gs, ai);
    }

    aG += __shfl_xor(aG, 1, 4); aG += __shfl_xor(aG, 2, 4);
    ah += __shfl_xor(ah, 1, 4); ah += __shfl_xor(ah, 2, 4);
    ai += __shfl_xor(ai, 1, 4); ai += __shfl_xor(ai, 2, 4);

    if (p == 0) {
        htabf[k] = ah;
        innertabf[k] = ai;
        float4 t; t.x = g_f32(x); t.y = x * aG; t.z = 0.0f; t.w = 0.0f;
        tab4[k] = t;
    }
}

// scalar f32 Catmull-Rom interp over a uniform table
__device__ __forceinline__ float interp1(const float* __restrict__ tab, float x) {
    float u = (x - XMINf) * INVDXf;
    u = fminf(fmaxf(u, 1.0f), (float)(NTAB - 3));
    int k = (int)u;
    if (k > NTAB - 3) k = NTAB - 3;
    float f = u - (float)k;
    float p0 = tab[k - 1], p1 = tab[k], p2 = tab[k + 1], p3 = tab[k + 2];
    return p1 + 0.5f * f * (p2 - p0 + f * (2.0f * p0 - 5.0f * p1 + 4.0f * p2 - p3
                 + f * (3.0f * (p1 - p2) + p3 - p0)));
}

// ================= init 2: H via outer rules over interpolated h/inner ==========
__global__ __launch_bounds__(256) void init_H() {
    int gid = blockIdx.x * blockDim.x + threadIdx.x;
    int k = gid >> 2, p = gid & 3;
    if (k >= NTAB) return;
    float x = XMINf + DXf * (float)k;

    float H;
    if (x < 0.0f) {
        // H_neg(x) = x * sum_i W_i h(x*a_i), chunk 8 of 32 per lane
        float acc = 0.0f;
        for (int i = 8 * p; i < 8 * p + 8; ++i)
            acc = fmaf(f_W32[i], interp1(htabf, x * f_A32[i]), acc);
        acc += __shfl_xor(acc, 1, 4); acc += __shfl_xor(acc, 2, 4);
        H = x * acc;
    } else {
        // H_pos(x) = C0*E(x) + x^2 sum_i W_i a_i e^{t^2} inner(t)
        float aE = 0.0f;
        for (int q = 12 * p; q < 12 * p + 12; ++q) {
            float t = x * f_A48[q];
            aE = fmaf(f_W48[q], __expf(t * t), aE);
        }
        float aS = 0.0f;
        for (int i = 8 * p; i < 8 * p + 8; ++i) {
            float t = x * f_A32[i];
            aS = fmaf(f_W32[i] * f_A32[i], __expf(t * t) * interp1(innertabf, t), aS);
        }
        aE += __shfl_xor(aE, 1, 4); aE += __shfl_xor(aE, 2, 4);
        aS += __shfl_xor(aS, 1, 4); aS += __shfl_xor(aS, 2, 4);
        H = f_C0 * (x * aE) + x * x * aS;
    }
    if (p == 0) tab4[k].z = H;
}

// ================= main kernel: packed float4 cubic lookups =================
__device__ __forceinline__ void cr_weights(float x, int* kk, float* w) {
    float u = (x - XMINf) * INVDXf;
    u = fminf(fmaxf(u, 1.0f), (float)(NTAB - 3));
    int k = (int)u;
    if (k > NTAB - 3) k = NTAB - 3;
    float f = u - (float)k;
    float f2 = f * f, f3 = f2 * f;
    w[0] = 0.5f * (-f + 2.0f * f2 - f3);
    w[1] = 1.0f + 0.5f * (-5.0f * f2 + 3.0f * f3);
    w[2] = 0.5f * (f + 4.0f * f2 - 3.0f * f3);
    w[3] = 0.5f * (f3 - f2);
    *kk = k;
}

__global__ __launch_bounds__(256) void mnn_main(const float* __restrict__ U,
        const float* __restrict__ S, float* __restrict__ out, int n) {
    int idx = blockIdx.x * blockDim.x + threadIdx.x;
    if (idx >= n) return;
    float u = U[idx], s = S[idx];
    float ua = 0.0f, sa = 0.0f, chi = 0.0f;

    bool sgt0 = (s > 0.0f);
    bool reg1 = sgt0 && ((1.0f - u) < 10.0f * SLf * s);   // VT*L = 1

    if (reg1) {
        float inv = 1.0f / (SLf * s);
        float ub = (1.0f - u) * inv;
        float lb = -u * inv;                    // always <= 0

        int ku, kl; float wu[4], wl[4];
        cr_weights(ub, &ku, wu);
        cr_weights(lb, &kl, wl);
        float4 a0 = tab4[ku - 1], a1 = tab4[ku], a2 = tab4[ku + 1], a3 = tab4[ku + 2];
        float4 b0 = tab4[kl - 1], b1 = tab4[kl], b2 = tab4[kl + 1], b3 = tab4[kl + 2];

        float g_ub = wu[0]*a0.x + wu[1]*a1.x + wu[2]*a2.x + wu[3]*a3.x;
        float G_ub = wu[0]*a0.y + wu[1]*a1.y + wu[2]*a2.y + wu[3]*a3.y;
        float H_ub = wu[0]*a0.z + wu[1]*a1.z + wu[2]*a2.z + wu[3]*a3.z;
        float g_lb = wl[0]*b0.x + wl[1]*b1.x + wl[2]*b2.x + wl[3]*b3.x;
        float G_lb = wl[0]*b0.y + wl[1]*b1.y + wl[2]*b2.y + wl[3]*b3.y;
        float H_lb = wl[0]*b0.z + wl[1]*b1.z + wl[2]*b2.z + wl[3]*b3.z;

        float dG = G_ub - G_lb;
        float ua1 = 1.0f / (40.0f * dG + 5.0f); // (2/L)*dG + TREF
        float dH = H_ub - H_lb;

        float fano = 3200.0f * dH * ua1 * ua1;  // 8/L^2
        float val = fano * ua1;
        float s_a = (val > 0.0f) ? sqrtf(val) : 0.0f;

        float dg = g_ub - g_lb;
        float sa_safe = (s_a > 0.0f) ? s_a : 1.0f;
        chi = ua1 * ua1 * dg * 178.88543819998318f / sa_safe;  // 2/L^1.5
        ua = ua1; sa = s_a;
    } else if (!sgt0 && u > 1.0f) {            // region 2
        float logt = 5.0f - 20.0f * logf(1.0f - 1.0f / u);
        ua = 1.0f / logt;
        chi = 6.324555320336759f / (sqrtf(logt) * sqrtf(2.0f * u - 1.0f)); // sqrt(40)
    }

    out[idx] = ua;
    out[n + idx] = sa;
    out[2 * n + idx] = chi;
}

// ================= launch =================
extern "C" void kernel_launch(void* const* d_in, const int* in_sizes, int n_in,
                              void* d_out, int out_size, void* d_ws, size_t ws_size,
                              hipStream_t stream) {
    const float* u = (const float*)d_in[0];
    const float* s = (const float*)d_in[1];
    float* out = (float*)d_out;
    int n = in_sizes[0];

    init_nodes<<<dim3(1), dim3(256), 0, stream>>>();
    init_tabs<<<dim3((NTAB * 4 + 255) / 256), dim3(256), 0, stream>>>();
    init_H<<<dim3((NTAB * 4 + 255) / 256), dim3(256), 0, stream>>>();
    mnn_main<<<dim3((n + 255) / 256), dim3(256), 0, stream>>>(u, s, out, n);
}

// Round 5
// 29.134 us; speedup vs baseline: 12.8288x; 1.0474x over previous
//
#include <hip/hip_runtime.h>
#include <math.h>

// ---- constants ----
#define SLf   0.22360679774997896f   // sqrt(L), L = 0.05

// ---- table geometry ----
#define NTAB   2048
#define XMINf  -17.0f
#define DXf    (23.0f / 2047.0f)
#define INVDXf (2047.0f / 23.0f)

__device__ float4 tab4[NTAB];      // .x = g, .y = G, .z = H

// ================= f64 g (only for C0) =================
__device__ double g_dbl(double x) {
    if (x >= -3.0) return 0.8862269254527580 * exp(x * x) * (1.0 + erf(x));
    double z = -x, iz2 = 1.0 / (z * z);
    return (0.5 / z) * (1.0 + iz2 * (-0.5 + iz2 * (0.75 - 1.875 * iz2)));
}

// ================= f32 g: erfc-based, cancellation-free =================
__device__ __forceinline__ float g_f32(float x) {
    if (x >= -3.0f) {
        // sqrt(pi)/2 * e^{x^2} * (1+erf(x)) = C * e^{x^2} * erfc(-x)
        return 0.88622692545275801f * __expf(x * x) * erfcf(-x);
    }
    float z = -x, iz = 1.0f / z, iz2 = iz * iz;
    return 0.5f * iz * (1.0f + iz2 * (-0.5f + iz2 * (0.75f - 1.875f * iz2)));
}

// ========== GL node solve (f64 Newton, Tricomi-ish init, 4 iters) ==========
template <int N>
__device__ void gl_node_t(int i, const double* __restrict__ inv, double* x01, double* w01) {
    double z = cos(3.14159265358979323846 * ((double)i + 0.75) / ((double)N + 0.5));
    double pl, pm, pp;
    for (int it = 0; it < 4; ++it) {
        pm = 1.0; pl = z;
        #pragma unroll
        for (int k = 2; k <= N; ++k) {
            double pk = ((2.0 * k - 1.0) * z * pl - (k - 1.0) * pm) * inv[k];
            pm = pl; pl = pk;
        }
        pp = (double)N * (z * pl - pm) / (z * z - 1.0);
        z -= pl / pp;
    }
    pm = 1.0; pl = z;
    #pragma unroll
    for (int k = 2; k <= N; ++k) {
        double pk = ((2.0 * k - 1.0) * z * pl - (k - 1.0) * pm) * inv[k];
        pm = pl; pl = pk;
    }
    pp = (double)N * (z * pl - pm) / (z * z - 1.0);
    *x01 = 0.5 * (z + 1.0);
    *w01 = 1.0 / ((1.0 - z * z) * pp * pp);   // weight mapped to [0,1]
}

// ============ single init kernel: nodes (redundant per block) + tables ==========
// 256 blocks x 256 threads; block b builds entries [8b, 8b+8), 32 lanes/entry.
__global__ __launch_bounds__(256) void build_tables() {
    __shared__ double s_inv[65];
    __shared__ float sA48[48], sW48[48];
    __shared__ float sA32[32], sW32[32], sR32[32], sWQ[32];
    __shared__ float sC0;
    int tid = threadIdx.x;
    if (tid >= 2 && tid <= 64) s_inv[tid] = 1.0 / (double)tid;
    __syncthreads();

    if (tid < 48) {                              // wave 0: GL-48
        double x, w; gl_node_t<48>(tid, s_inv, &x, &w);
        sA48[tid] = (float)x; sW48[tid] = (float)w;
    } else if (tid >= 64 && tid < 96) {          // wave 1: GL-32 (+derived)
        int j = tid - 64;
        double x, w; gl_node_t<32>(j, s_inv, &x, &w);
        sA32[j] = (float)x; sW32[j] = (float)w;
        sR32[j] = (float)(-log1p(-x));
        sWQ[j]  = (float)(w / (1.0 - x));
    } else if (tid >= 128 && tid < 192) {        // wave 2: GL-64 -> C0
        int j = tid - 128;
        double x, w; gl_node_t<64>(j, s_inv, &x, &w);
        double r = -log1p(-x);
        double gv = g_dbl(-r);
        double term = w * exp(-r * r) * gv * gv / (1.0 - x);
        for (int off = 32; off > 0; off >>= 1)
            term += __shfl_down(term, off);
        if (j == 0) sC0 = (float)term;
    }
    __syncthreads();

    int k = blockIdx.x * 8 + (tid >> 5);         // table entry
    int i = tid & 31;                            // lane within entry
    float x = XMINf + DXf * (float)k;

    // G partial: nodes i and i+32 (48 nodes over 32 lanes)
    float aG = sW48[i] * g_f32(x * sA48[i]);
    if (i < 16) aG = fmaf(sW48[i + 32], g_f32(x * sA48[i + 32]), aG);

    float Hp, aE = 0.0f;
    float t = x * sA32[i];
    if (x < 0.0f) {
        // H_neg partial: W_i * h(t), h via 32-pt r-mapped rule (ref _h_neg)
        float h = 0.0f;
        for (int j = 0; j < 32; ++j) {
            float r = sR32[j];
            float gg = g_f32(t - r);             // arg <= 0 always
            h = fmaf(sWQ[j], __expf((2.0f * t - r) * r) * gg * gg, h);
        }
        Hp = sW32[i] * h;
    } else {
        // H_pos partial: W_i a_i e^{t^2} * inner(t) (ref H_pos)
        float inner = 0.0f;
        for (int j = 0; j < 32; ++j) {
            float s = t * sA32[j];
            float gs = g_f32(s);
            inner = fmaf(sW32[j], __expf(-s * s) * gs * gs, inner);
        }
        Hp = sW32[i] * sA32[i] * __expf(t * t) * inner;
        // E partial (48 nodes over 32 lanes)
        float t0 = x * sA48[i];
        aE = sW48[i] * __expf(t0 * t0);
        if (i < 16) {
            float t1 = x * sA48[i + 32];
            aE = fmaf(sW48[i + 32], __expf(t1 * t1), aE);
        }
    }

    // butterfly reduce within each 32-lane entry group
    #pragma unroll
    for (int off = 16; off > 0; off >>= 1) {
        aG += __shfl_xor(aG, off, 32);
        Hp += __shfl_xor(Hp, off, 32);
        aE += __shfl_xor(aE, off, 32);
    }

    if (i == 0) {
        float Hv = (x < 0.0f) ? x * Hp
                              : sC0 * (x * aE) + x * x * Hp;
        float4 e; e.x = g_f32(x); e.y = x * aG; e.z = Hv; e.w = 0.0f;
        tab4[k] = e;
    }
}

// ================= main kernel: packed float4 cubic lookups =================
__device__ __forceinline__ void cr_weights(float x, int* kk, float* w) {
    float u = (x - XMINf) * INVDXf;
    u = fminf(fmaxf(u, 1.0f), (float)(NTAB - 3));
    int k = (int)u;
    if (k > NTAB - 3) k = NTAB - 3;
    float f = u - (float)k;
    float f2 = f * f, f3 = f2 * f;
    w[0] = 0.5f * (-f + 2.0f * f2 - f3);
    w[1] = 1.0f + 0.5f * (-5.0f * f2 + 3.0f * f3);
    w[2] = 0.5f * (f + 4.0f * f2 - 3.0f * f3);
    w[3] = 0.5f * (f3 - f2);
    *kk = k;
}

__global__ __launch_bounds__(256) void mnn_main(const float* __restrict__ U,
        const float* __restrict__ S, float* __restrict__ out, int n) {
    int idx = blockIdx.x * blockDim.x + threadIdx.x;
    if (idx >= n) return;
    float u = U[idx], s = S[idx];
    float ua = 0.0f, sa = 0.0f, chi = 0.0f;

    bool sgt0 = (s > 0.0f);
    bool reg1 = sgt0 && ((1.0f - u) < 10.0f * SLf * s);   // VT*L = 1

    if (reg1) {
        float inv = 1.0f / (SLf * s);
        float ub = (1.0f - u) * inv;
        float lb = -u * inv;                    // always <= 0

        int ku, kl; float wu[4], wl[4];
        cr_weights(ub, &ku, wu);
        cr_weights(lb, &kl, wl);
        float4 a0 = tab4[ku - 1], a1 = tab4[ku], a2 = tab4[ku + 1], a3 = tab4[ku + 2];
        float4 b0 = tab4[kl - 1], b1 = tab4[kl], b2 = tab4[kl + 1], b3 = tab4[kl + 2];

        float g_ub = wu[0]*a0.x + wu[1]*a1.x + wu[2]*a2.x + wu[3]*a3.x;
        float G_ub = wu[0]*a0.y + wu[1]*a1.y + wu[2]*a2.y + wu[3]*a3.y;
        float H_ub = wu[0]*a0.z + wu[1]*a1.z + wu[2]*a2.z + wu[3]*a3.z;
        float g_lb = wl[0]*b0.x + wl[1]*b1.x + wl[2]*b2.x + wl[3]*b3.x;
        float G_lb = wl[0]*b0.y + wl[1]*b1.y + wl[2]*b2.y + wl[3]*b3.y;
        float H_lb = wl[0]*b0.z + wl[1]*b1.z + wl[2]*b2.z + wl[3]*b3.z;

        float dG = G_ub - G_lb;
        float ua1 = 1.0f / (40.0f * dG + 5.0f); // (2/L)*dG + TREF
        float dH = H_ub - H_lb;

        float fano = 3200.0f * dH * ua1 * ua1;  // 8/L^2
        float val = fano * ua1;
        float s_a = (val > 0.0f) ? sqrtf(val) : 0.0f;

        float dg = g_ub - g_lb;
        float sa_safe = (s_a > 0.0f) ? s_a : 1.0f;
        chi = ua1 * ua1 * dg * 178.88543819998318f / sa_safe;  // 2/L^1.5
        ua = ua1; sa = s_a;
    } else if (!sgt0 && u > 1.0f) {            // region 2
        float logt = 5.0f - 20.0f * logf(1.0f - 1.0f / u);
        ua = 1.0f / logt;
        chi = 6.324555320336759f / (sqrtf(logt) * sqrtf(2.0f * u - 1.0f)); // sqrt(40)
    }

    out[idx] = ua;
    out[n + idx] = sa;
    out[2 * n + idx] = chi;
}

// ================= launch =================
extern "C" void kernel_launch(void* const* d_in, const int* in_sizes, int n_in,
                              void* d_out, int out_size, void* d_ws, size_t ws_size,
                              hipStream_t stream) {
    const float* u = (const float*)d_in[0];
    const float* s = (const float*)d_in[1];
    float* out = (float*)d_out;
    int n = in_sizes[0];

    build_tables<<<dim3(NTAB / 8), dim3(256), 0, stream>>>();
    mnn_main<<<dim3((n + 255) / 256), dim3(256), 0, stream>>>(u, s, out, n);
}

// Round 7
// 26.877 us; speedup vs baseline: 13.9061x; 1.0840x over previous
//
#include <hip/hip_runtime.h>
#include <math.h>

// ---- constants ----
#define SLf   0.22360679774997896f   // sqrt(L), L = 0.05

// ---- table geometry ----
#define NTAB   1024
#define XMINf  -17.0f
#define DXf    (23.0f / 1023.0f)
#define INVDXf (1023.0f / 23.0f)

__device__ float4 tab4[NTAB];      // .x = g, .y = G, .z = H

// ================= f64 g (only for C0) =================
__device__ double g_dbl(double x) {
    if (x >= -3.0) return 0.8862269254527580 * exp(x * x) * (1.0 + erf(x));
    double z = -x, iz2 = 1.0 / (z * z);
    return (0.5 / z) * (1.0 + iz2 * (-0.5 + iz2 * (0.75 - 1.875 * iz2)));
}

// ================= f32 g: erfc-based, cancellation-free =================
__device__ __forceinline__ float g_f32(float x) {
    if (x >= -3.0f) {
        // sqrt(pi)/2 * e^{x^2} * (1+erf(x)) = C * e^{x^2} * erfc(-x)
        return 0.88622692545275801f * __expf(x * x) * erfcf(-x);
    }
    float z = -x, iz = 1.0f / z, iz2 = iz * iz;
    return 0.5f * iz * (1.0f + iz2 * (-0.5f + iz2 * (0.75f - 1.875f * iz2)));
}

// ========== GL node solve (f64 Newton, Tricomi init, 2 iters + final) ==========
template <int N>
__device__ void gl_node_t(int i, const double* __restrict__ inv, double* x01, double* w01) {
    double z = cos(3.14159265358979323846 * ((double)i + 0.75) / ((double)N + 0.5));
    double pl, pm, pp;
    for (int it = 0; it < 2; ++it) {
        pm = 1.0; pl = z;
        #pragma unroll
        for (int k = 2; k <= N; ++k) {
            double pk = ((2.0 * k - 1.0) * z * pl - (k - 1.0) * pm) * inv[k];
            pm = pl; pl = pk;
        }
        pp = (double)N * (z * pl - pm) / (z * z - 1.0);
        z -= pl / pp;
    }
    pm = 1.0; pl = z;
    #pragma unroll
    for (int k = 2; k <= N; ++k) {
        double pk = ((2.0 * k - 1.0) * z * pl - (k - 1.0) * pm) * inv[k];
        pm = pl; pl = pk;
    }
    pp = (double)N * (z * pl - pm) / (z * z - 1.0);
    *x01 = 0.5 * (z + 1.0);
    *w01 = 1.0 / ((1.0 - z * z) * pp * pp);   // weight mapped to [0,1]
}

// ============ single init kernel: GL nodes (redundant per block) + tables =======
// 256 blocks x 128 threads (2 waves); block b builds entries [4b, 4b+4), 32 lanes each.
// Wave 0 lanes 0-47: GL-48 Newton.  Wave 1 lanes 0-31 (tid 64-95): GL-32 Newton + C0.
__global__ __launch_bounds__(128) void build_tables() {
    __shared__ double s_inv[65];
    __shared__ float sA48[48], sW48[48];
    __shared__ float sA32[32], sW32[32], sR32[32], sWQ[32];
    __shared__ float sC0;
    int tid = threadIdx.x;
    if (tid >= 2 && tid <= 64) s_inv[tid] = 1.0 / (double)tid;
    __syncthreads();

    if (tid < 48) {                              // wave 0: GL-48
        double x, w; gl_node_t<48>(tid, s_inv, &x, &w);
        sA48[tid] = (float)x; sW48[tid] = (float)w;
    } else if (tid >= 64 && tid < 96) {          // wave 1: GL-32 (+derived +C0)
        int j = tid - 64;
        double x, w; gl_node_t<32>(j, s_inv, &x, &w);
        sA32[j] = (float)x; sW32[j] = (float)w;
        sR32[j] = (float)(-log1p(-x));
        sWQ[j]  = (float)(w / (1.0 - x));
        // C0 = int_{-inf}^0 e^{-s^2} g(s)^2 ds via the same 32-pt r-mapped rule
        // (this integrand is smooth & converged at 32 pts, unlike E/H's e^{t^2})
        double r = -log1p(-x);
        double gv = g_dbl(-r);
        double term = w * exp(-r * r) * gv * gv / (1.0 - x);
        #pragma unroll
        for (int off = 16; off > 0; off >>= 1)
            term += __shfl_down(term, off, 32);
        if (j == 0) sC0 = (float)term;
    }
    __syncthreads();

    int k = blockIdx.x * 4 + (tid >> 5);         // table entry
    int i = tid & 31;                            // lane within entry
    float x = XMINf + DXf * (float)k;

    // G partial: nodes i and i+32 (48 nodes over 32 lanes)
    float aG = sW48[i] * g_f32(x * sA48[i]);
    if (i < 16) aG = fmaf(sW48[i + 32], g_f32(x * sA48[i + 32]), aG);

    float Hp, aE = 0.0f;
    float t = x * sA32[i];
    if (x < 0.0f) {
        // H_neg partial: W_i * h(t), h via 32-pt r-mapped rule (ref _h_neg)
        float h = 0.0f;
        for (int j = 0; j < 32; ++j) {
            float r = sR32[j];
            float gg = g_f32(t - r);             // arg <= 0 always
            h = fmaf(sWQ[j], __expf((2.0f * t - r) * r) * gg * gg, h);
        }
        Hp = sW32[i] * h;
    } else {
        // H_pos partial: W_i a_i e^{t^2} * inner(t) (ref H_pos)
        float inner = 0.0f;
        for (int j = 0; j < 32; ++j) {
            float s = t * sA32[j];
            float gs = g_f32(s);
            inner = fmaf(sW32[j], __expf(-s * s) * gs * gs, inner);
        }
        Hp = sW32[i] * sA32[i] * __expf(t * t) * inner;
        // E partial (48 nodes over 32 lanes)
        float t0 = x * sA48[i];
        aE = sW48[i] * __expf(t0 * t0);
        if (i < 16) {
            float t1 = x * sA48[i + 32];
            aE = fmaf(sW48[i + 32], __expf(t1 * t1), aE);
        }
    }

    // butterfly reduce within each 32-lane entry group
    #pragma unroll
    for (int off = 16; off > 0; off >>= 1) {
        aG += __shfl_xor(aG, off, 32);
        Hp += __shfl_xor(Hp, off, 32);
        aE += __shfl_xor(aE, off, 32);
    }

    if (i == 0) {
        float Hv = (x < 0.0f) ? x * Hp
                              : sC0 * (x * aE) + x * x * Hp;
        float4 e; e.x = g_f32(x); e.y = x * aG; e.z = Hv; e.w = 0.0f;
        tab4[k] = e;
    }
}

// ================= main kernel: packed float4 cubic lookups =================
__device__ __forceinline__ void cr_weights(float x, int* kk, float* w) {
    float u = (x - XMINf) * INVDXf;
    u = fminf(fmaxf(u, 1.0f), (float)(NTAB - 3));
    int k = (int)u;
    if (k > NTAB - 3) k = NTAB - 3;
    float f = u - (float)k;
    float f2 = f * f, f3 = f2 * f;
    w[0] = 0.5f * (-f + 2.0f * f2 - f3);
    w[1] = 1.0f + 0.5f * (-5.0f * f2 + 3.0f * f3);
    w[2] = 0.5f * (f + 4.0f * f2 - 3.0f * f3);
    w[3] = 0.5f * (f3 - f2);
    *kk = k;
}

__global__ __launch_bounds__(256) void mnn_main(const float* __restrict__ U,
        const float* __restrict__ S, float* __restrict__ out, int n) {
    int idx = blockIdx.x * blockDim.x + threadIdx.x;
    if (idx >= n) return;
    float u = U[idx], s = S[idx];
    float ua = 0.0f, sa = 0.0f, chi = 0.0f;

    bool sgt0 = (s > 0.0f);
    bool reg1 = sgt0 && ((1.0f - u) < 10.0f * SLf * s);   // VT*L = 1

    if (reg1) {
        float inv = 1.0f / (SLf * s);
        float ub = (1.0f - u) * inv;
        float lb = -u * inv;                    // always <= 0

        int ku, kl; float wu[4], wl[4];
        cr_weights(ub, &ku, wu);
        cr_weights(lb, &kl, wl);
        float4 a0 = tab4[ku - 1], a1 = tab4[ku], a2 = tab4[ku + 1], a3 = tab4[ku + 2];
        float4 b0 = tab4[kl - 1], b1 = tab4[kl], b2 = tab4[kl + 1], b3 = tab4[kl + 2];

        float g_ub = wu[0]*a0.x + wu[1]*a1.x + wu[2]*a2.x + wu[3]*a3.x;
        float G_ub = wu[0]*a0.y + wu[1]*a1.y + wu[2]*a2.y + wu[3]*a3.y;
        float H_ub = wu[0]*a0.z + wu[1]*a1.z + wu[2]*a2.z + wu[3]*a3.z;
        float g_lb = wl[0]*b0.x + wl[1]*b1.x + wl[2]*b2.x + wl[3]*b3.x;
        float G_lb = wl[0]*b0.y + wl[1]*b1.y + wl[2]*b2.y + wl[3]*b3.y;
        float H_lb = wl[0]*b0.z + wl[1]*b1.z + wl[2]*b2.z + wl[3]*b3.z;

        float dG = G_ub - G_lb;
        float ua1 = 1.0f / (40.0f * dG + 5.0f); // (2/L)*dG + TREF
        float dH = H_ub - H_lb;

        float fano = 3200.0f * dH * ua1 * ua1;  // 8/L^2
        float val = fano * ua1;
        float s_a = (val > 0.0f) ? sqrtf(val) : 0.0f;

        float dg = g_ub - g_lb;
        float sa_safe = (s_a > 0.0f) ? s_a : 1.0f;
        chi = ua1 * ua1 * dg * 178.88543819998318f / sa_safe;  // 2/L^1.5
        ua = ua1; sa = s_a;
    } else if (!sgt0 && u > 1.0f) {            // region 2
        float logt = 5.0f - 20.0f * logf(1.0f - 1.0f / u);
        ua = 1.0f / logt;
        chi = 6.324555320336759f / (sqrtf(logt) * sqrtf(2.0f * u - 1.0f)); // sqrt(40)
    }

    out[idx] = ua;
    out[n + idx] = sa;
    out[2 * n + idx] = chi;
}

// ================= launch =================
extern "C" void kernel_launch(void* const* d_in, const int* in_sizes, int n_in,
                              void* d_out, int out_size, void* d_ws, size_t ws_size,
                              hipStream_t stream) {
    const float* u = (const float*)d_in[0];
    const float* s = (const float*)d_in[1];
    float* out = (float*)d_out;
    int n = in_sizes[0];

    build_tables<<<dim3(NTAB / 4), dim3(128), 0, stream>>>();
    mnn_main<<<dim3((n + 255) / 256), dim3(256), 0, stream>>>(u, s, out, n);
}